// Round 1
// baseline (33.807 us; speedup 1.0000x reference)
//
#include <hip/hip_runtime.h>
#include <hip/hip_bf16.h>

// Graph3DBias: B=8, N=256, K=128, EMBED=768
// out[b,i,d] = mask_i * ( sum_k proj_w[d,k] * S[b,i,k] + proj_b[d] )
// S[b,i,k]   = sum_j mask_j * exp(-0.5*((y_bij - mean_k)/std_k)^2) / (sqrt(2pi)*std_k)
// y_bij      = mul_w[ai*128+aj] * dist(b,i,j) + bias_w[ai*128+aj]

#define NN 256          // nodes per batch
#define KK 128          // gaussian kernels
#define DD 768          // embed dim

// ---------------- Kernel 1: per-(b,i) gaussian accumulation ----------------
// grid = B*N blocks, 256 threads. Thread t: k = t&127, j-half = t>>7.
__global__ __launch_bounds__(256) void k_edges(
    const float* __restrict__ pos,     // (B,N,3)
    const int*   __restrict__ xatom,   // (B,N)
    const float* __restrict__ means,   // (K)
    const float* __restrict__ stds,    // (K)
    const float* __restrict__ mul_w,   // (1536)
    const float* __restrict__ bias_w,  // (1536)
    float* __restrict__ sumef)         // (B*N, K)
{
    const int bi = blockIdx.x;
    const int b  = bi >> 8;
    const int t  = threadIdx.x;
    const int base = b << 8;

    __shared__ __align__(16) float y_sh[NN];
    __shared__ float part[256];

    const int   ai  = xatom[bi];
    const float pix = pos[bi*3+0], piy = pos[bi*3+1], piz = pos[bi*3+2];

    {   // each thread computes y for j = t
        const int j  = t;
        const int aj = xatom[base + j];
        const float dx = pix - pos[(base+j)*3+0];
        const float dy = piy - pos[(base+j)*3+1];
        const float dz = piz - pos[(base+j)*3+2];
        const float dist = sqrtf(dx*dx + dy*dy + dz*dz);
        const int idx = ai*128 + aj;
        float y = mul_w[idx]*dist + bias_w[idx];
        if (aj == 0) y = 1e20f;   // padded j -> exp underflows to 0
        y_sh[j] = y;
    }
    __syncthreads();

    const int k    = t & 127;
    const int half = t >> 7;
    const float m   = means[k];
    const float s   = fabsf(stds[k]) + 0.8f;
    const float inv = 1.0f / s;
    // exp(-0.5*((y-m)/s)^2) = exp2(-(d^2)), d = (y-m)*inv*sqrt(0.5*log2e)
    const float w   = inv * 0.84932160f;     // sqrt(0.5*1.44269504)
    const float nm  = -m * w;
    const float c   = inv * 0.39894253f;     // 1/sqrt(2*3.14159)  (PI as in ref)

    float a0=0.f, a1=0.f, a2=0.f, a3=0.f;
    const float4* yv = (const float4*)(y_sh + (half << 7));
    #pragma unroll
    for (int j4 = 0; j4 < 32; ++j4) {
        float4 y4 = yv[j4];
        float d0 = fmaf(y4.x, w, nm); a0 += exp2f(-(d0*d0));
        float d1 = fmaf(y4.y, w, nm); a1 += exp2f(-(d1*d1));
        float d2 = fmaf(y4.z, w, nm); a2 += exp2f(-(d2*d2));
        float d3 = fmaf(y4.w, w, nm); a3 += exp2f(-(d3*d3));
    }
    part[t] = ((a0+a1)+(a2+a3)) * c;
    __syncthreads();

    if (t < 128)
        sumef[bi*KK + t] = part[t] + part[t + 128];
}

// ---------------- Kernel 2: projection GEMM (2048x128 @ 768x128^T) ----------
// 64x64 tiles, 256 threads, 4x4 register blocking, K=128 single pass.
__global__ __launch_bounds__(256) void k_proj(
    const float* __restrict__ sumef,   // (2048,128)
    const float* __restrict__ proj_w,  // (768,128)
    const float* __restrict__ proj_b,  // (768)
    const int*   __restrict__ xatom,   // (2048)
    float* __restrict__ out)           // (2048,768)
{
    __shared__ __align__(16) float As[64*132];   // [row][k], stride 132
    __shared__ __align__(16) float Bs[128*68];   // [k][d],  stride 68

    const int t    = threadIdx.x;
    const int row0 = (blockIdx.x & 31) << 6;     // 32 row tiles
    const int d0   = (blockIdx.x >> 5) << 6;     // 12 col tiles

    // stage A tile: 64 rows x 128 k  (coalesced float4 reads)
    {
        const float4* src = (const float4*)(sumef + row0*KK);
        #pragma unroll
        for (int it = 0; it < 8; ++it) {
            int c = t + (it << 8);
            int r = c >> 5, kq = c & 31;
            float4 v = src[c];
            float* dst = &As[r*132 + (kq<<2)];
            dst[0]=v.x; dst[1]=v.y; dst[2]=v.z; dst[3]=v.w;
        }
    }
    // stage B tile transposed: proj_w[d][k] -> Bs[k][d]
    {
        const float4* src = (const float4*)(proj_w + d0*KK);
        #pragma unroll
        for (int it = 0; it < 8; ++it) {
            int c = t + (it << 8);
            int d = c >> 5, kq = c & 31;
            float4 v = src[c];
            Bs[((kq<<2)+0)*68 + d] = v.x;
            Bs[((kq<<2)+1)*68 + d] = v.y;
            Bs[((kq<<2)+2)*68 + d] = v.z;
            Bs[((kq<<2)+3)*68 + d] = v.w;
        }
    }
    __syncthreads();

    const int tr = t >> 4, tc = t & 15;
    float acc[4][4] = {};
    const float4* As4 = (const float4*)As;   // row stride 33
    const float4* Bs4 = (const float4*)Bs;   // row stride 17

    for (int k4 = 0; k4 < 32; ++k4) {
        float ar[4][4], br[4][4];
        #pragma unroll
        for (int s = 0; s < 4; ++s) {
            float4 a = As4[(tr*4+s)*33 + k4];     // A[row=tr*4+s][k4*4..+3]
            ar[s][0]=a.x; ar[s][1]=a.y; ar[s][2]=a.z; ar[s][3]=a.w;
        }
        #pragma unroll
        for (int q = 0; q < 4; ++q) {
            float4 bq = Bs4[(k4*4+q)*17 + tc];    // B[k=k4*4+q][d=tc*4..+3]
            br[q][0]=bq.x; br[q][1]=bq.y; br[q][2]=bq.z; br[q][3]=bq.w;
        }
        #pragma unroll
        for (int s = 0; s < 4; ++s)
            #pragma unroll
            for (int q = 0; q < 4; ++q)
                #pragma unroll
                for (int u = 0; u < 4; ++u)
                    acc[s][u] = fmaf(ar[s][q], br[q][u], acc[s][u]);
    }

    const float4 pb = *(const float4*)(proj_b + d0 + (tc<<2));
    #pragma unroll
    for (int s = 0; s < 4; ++s) {
        const int row = row0 + tr*4 + s;
        const bool valid = (xatom[row] != 0);
        float4 o;
        o.x = valid ? acc[s][0] + pb.x : 0.0f;
        o.y = valid ? acc[s][1] + pb.y : 0.0f;
        o.z = valid ? acc[s][2] + pb.z : 0.0f;
        o.w = valid ? acc[s][3] + pb.w : 0.0f;
        *(float4*)(out + row*DD + d0 + (tc<<2)) = o;
    }
}

extern "C" void kernel_launch(void* const* d_in, const int* in_sizes, int n_in,
                              void* d_out, int out_size, void* d_ws, size_t ws_size,
                              hipStream_t stream) {
    const float* pos    = (const float*)d_in[0];
    const int*   xatom  = (const int*)  d_in[1];
    const float* means  = (const float*)d_in[2];
    const float* stds   = (const float*)d_in[3];
    const float* mul_w  = (const float*)d_in[4];
    const float* bias_w = (const float*)d_in[5];
    const float* proj_w = (const float*)d_in[6];
    const float* proj_b = (const float*)d_in[7];
    float* out   = (float*)d_out;
    float* sumef = (float*)d_ws;                 // 2048*128*4 = 1 MB scratch

    const int BN = in_sizes[1];                  // B*N = 2048

    k_edges<<<BN, 256, 0, stream>>>(pos, xatom, means, stds, mul_w, bias_w, sumef);
    k_proj<<<(BN/64)*(DD/64), 256, 0, stream>>>(sumef, proj_w, proj_b, xatom, out);
}

// Round 2
// 27.004 us; speedup vs baseline: 1.2519x; 1.2519x over previous
//
#include <hip/hip_runtime.h>
#include <hip/hip_bf16.h>

// Graph3DBias: B=8, N=256, K=128, EMBED=768
// out[b,i,d] = mask_i * ( sum_k proj_w[d,k] * S[b,i,k] + proj_b[d] )
// S[b,i,k]   = sum_j mask_j * exp(-0.5*((y_bij - mean_k)/std_k)^2) / (sqrt(2pi)*std_k)
// y_bij      = mul_w[ai*128+aj] * dist(b,i,j) + bias_w[ai*128+aj]

#define NN 256          // nodes per batch
#define KK 128          // gaussian kernels
#define DD 768          // embed dim

// ---------------- Kernel 1: per-(b,i) gaussian accumulation ----------------
// grid = B*N blocks, 256 threads. Thread t: k = t&127, j-half = t>>7.
__global__ __launch_bounds__(256) void k_edges(
    const float* __restrict__ pos,     // (B,N,3)
    const int*   __restrict__ xatom,   // (B,N)
    const float* __restrict__ means,   // (K)
    const float* __restrict__ stds,    // (K)
    const float* __restrict__ mul_w,   // (1536)
    const float* __restrict__ bias_w,  // (1536)
    float* __restrict__ sumef)         // (B*N, K)
{
    const int bi = blockIdx.x;
    const int b  = bi >> 8;
    const int t  = threadIdx.x;
    const int base = b << 8;

    __shared__ __align__(16) float y_sh[NN];
    __shared__ float part[256];

    const int   ai  = xatom[bi];
    const float pix = pos[bi*3+0], piy = pos[bi*3+1], piz = pos[bi*3+2];

    {   // each thread computes y for j = t
        const int j  = t;
        const int aj = xatom[base + j];
        const float dx = pix - pos[(base+j)*3+0];
        const float dy = piy - pos[(base+j)*3+1];
        const float dz = piz - pos[(base+j)*3+2];
        const float dist = sqrtf(dx*dx + dy*dy + dz*dz);
        const int idx = ai*128 + aj;
        float y = mul_w[idx]*dist + bias_w[idx];
        if (aj == 0) y = 1e20f;   // padded j -> exp underflows to 0
        y_sh[j] = y;
    }
    __syncthreads();

    const int k    = t & 127;
    const int half = t >> 7;
    const float m   = means[k];
    const float s   = fabsf(stds[k]) + 0.8f;
    const float inv = 1.0f / s;
    // exp(-0.5*((y-m)/s)^2) = exp2(-(d^2)), d = (y-m)*inv*sqrt(0.5*log2e)
    const float w   = inv * 0.84932160f;     // sqrt(0.5*1.44269504)
    const float nm  = -m * w;
    const float c   = inv * 0.39894253f;     // 1/sqrt(2*3.14159)  (PI as in ref)

    float a0=0.f, a1=0.f, a2=0.f, a3=0.f;
    const float4* yv = (const float4*)(y_sh + (half << 7));
    #pragma unroll
    for (int j4 = 0; j4 < 32; ++j4) {
        float4 y4 = yv[j4];
        // raw v_exp_f32: arg is always <= 0; underflow flushes to 0 which is
        // exactly what the reference's masked/far-tail values produce.
        float d0 = fmaf(y4.x, w, nm); a0 += __builtin_amdgcn_exp2f(-(d0*d0));
        float d1 = fmaf(y4.y, w, nm); a1 += __builtin_amdgcn_exp2f(-(d1*d1));
        float d2 = fmaf(y4.z, w, nm); a2 += __builtin_amdgcn_exp2f(-(d2*d2));
        float d3 = fmaf(y4.w, w, nm); a3 += __builtin_amdgcn_exp2f(-(d3*d3));
    }
    part[t] = ((a0+a1)+(a2+a3)) * c;
    __syncthreads();

    if (t < 128)
        sumef[bi*KK + t] = part[t] + part[t + 128];
}

// ---------------- Kernel 2: projection GEMM (2048x128 @ 768x128^T) ----------
// 64x64 tiles, 256 threads, 4x4 register blocking, K=128 single pass.
__global__ __launch_bounds__(256) void k_proj(
    const float* __restrict__ sumef,   // (2048,128)
    const float* __restrict__ proj_w,  // (768,128)
    const float* __restrict__ proj_b,  // (768)
    const int*   __restrict__ xatom,   // (2048)
    float* __restrict__ out)           // (2048,768)
{
    __shared__ __align__(16) float As[64*132];   // [row][k], stride 132
    __shared__ __align__(16) float Bs[128*68];   // [k][d],  stride 68

    const int t    = threadIdx.x;
    const int row0 = (blockIdx.x & 31) << 6;     // 32 row tiles
    const int d0   = (blockIdx.x >> 5) << 6;     // 12 col tiles

    // stage A tile: 64 rows x 128 k  (coalesced float4 reads, float4 LDS store)
    {
        const float4* src = (const float4*)(sumef + row0*KK);
        #pragma unroll
        for (int it = 0; it < 8; ++it) {
            int c = t + (it << 8);
            int r = c >> 5, kq = c & 31;
            float4 v = src[c];
            *(float4*)&As[r*132 + (kq<<2)] = v;   // 132 = 4*33 -> 16B aligned
        }
    }
    // stage B tile transposed: proj_w[d][k] -> Bs[k][d]
    {
        const float4* src = (const float4*)(proj_w + d0*KK);
        #pragma unroll
        for (int it = 0; it < 8; ++it) {
            int c = t + (it << 8);
            int d = c >> 5, kq = c & 31;
            float4 v = src[c];
            Bs[((kq<<2)+0)*68 + d] = v.x;
            Bs[((kq<<2)+1)*68 + d] = v.y;
            Bs[((kq<<2)+2)*68 + d] = v.z;
            Bs[((kq<<2)+3)*68 + d] = v.w;
        }
    }
    __syncthreads();

    const int tr = t >> 4, tc = t & 15;
    float acc[4][4] = {};
    const float4* As4 = (const float4*)As;   // row stride 33
    const float4* Bs4 = (const float4*)Bs;   // row stride 17

    for (int k4 = 0; k4 < 32; ++k4) {
        float ar[4][4], br[4][4];
        #pragma unroll
        for (int s = 0; s < 4; ++s) {
            float4 a = As4[(tr*4+s)*33 + k4];     // broadcast across tc lanes
            ar[s][0]=a.x; ar[s][1]=a.y; ar[s][2]=a.z; ar[s][3]=a.w;
        }
        #pragma unroll
        for (int q = 0; q < 4; ++q) {
            float4 bq = Bs4[(k4*4+q)*17 + tc];    // 16 distinct addrs, 4-way bcast
            br[q][0]=bq.x; br[q][1]=bq.y; br[q][2]=bq.z; br[q][3]=bq.w;
        }
        #pragma unroll
        for (int s = 0; s < 4; ++s)
            #pragma unroll
            for (int q = 0; q < 4; ++q)
                #pragma unroll
                for (int u = 0; u < 4; ++u)
                    acc[s][u] = fmaf(ar[s][q], br[q][u], acc[s][u]);
    }

    const float4 pb = *(const float4*)(proj_b + d0 + (tc<<2));
    #pragma unroll
    for (int s = 0; s < 4; ++s) {
        const int row = row0 + tr*4 + s;
        const bool valid = (xatom[row] != 0);
        float4 o;
        o.x = valid ? acc[s][0] + pb.x : 0.0f;
        o.y = valid ? acc[s][1] + pb.y : 0.0f;
        o.z = valid ? acc[s][2] + pb.z : 0.0f;
        o.w = valid ? acc[s][3] + pb.w : 0.0f;
        *(float4*)(out + row*DD + d0 + (tc<<2)) = o;
    }
}

extern "C" void kernel_launch(void* const* d_in, const int* in_sizes, int n_in,
                              void* d_out, int out_size, void* d_ws, size_t ws_size,
                              hipStream_t stream) {
    const float* pos    = (const float*)d_in[0];
    const int*   xatom  = (const int*)  d_in[1];
    const float* means  = (const float*)d_in[2];
    const float* stds   = (const float*)d_in[3];
    const float* mul_w  = (const float*)d_in[4];
    const float* bias_w = (const float*)d_in[5];
    const float* proj_w = (const float*)d_in[6];
    const float* proj_b = (const float*)d_in[7];
    float* out   = (float*)d_out;
    float* sumef = (float*)d_ws;                 // 2048*128*4 = 1 MB scratch

    const int BN = in_sizes[1];                  // B*N = 2048

    k_edges<<<BN, 256, 0, stream>>>(pos, xatom, means, stds, mul_w, bias_w, sumef);
    k_proj<<<(BN/64)*(DD/64), 256, 0, stream>>>(sumef, proj_w, proj_b, xatom, out);
}

// Round 3
// 25.577 us; speedup vs baseline: 1.3218x; 1.0558x over previous
//
#include <hip/hip_runtime.h>
#include <hip/hip_bf16.h>
#include <hip/hip_fp16.h>

// Graph3DBias: B=8, N=256, K=128, EMBED=768
// out[b,i,d] = mask_i * ( sum_k proj_w[d,k] * S[b,i,k] + proj_b[d] )
// S[b,i,k]   = sum_j mask_j * exp(-0.5*((y_bij - mean_k)/std_k)^2) / (sqrt(2pi)*std_k)

#define NN 256
#define KK 128
#define DD 768

typedef _Float16 half8 __attribute__((ext_vector_type(8)));
typedef _Float16 half4v __attribute__((ext_vector_type(4)));
typedef float f32x4 __attribute__((ext_vector_type(4)));

// ---------------- Kernel 0: proj_w f32 -> fp16 ----------------
__global__ __launch_bounds__(256) void k_cvtw(const float* __restrict__ w,
                                              _Float16* __restrict__ wh) {
    const int i = (blockIdx.x * 256 + threadIdx.x) * 4;   // 98304 elements total
    float4 v = *(const float4*)(w + i);
    half4v h;
    h.x = (_Float16)v.x; h.y = (_Float16)v.y;
    h.z = (_Float16)v.z; h.w = (_Float16)v.w;
    *(half4v*)(wh + i) = h;
}

// ---------------- Kernel 1: per-(b,i) gaussian accumulation ----------------
__global__ __launch_bounds__(256) void k_edges(
    const float* __restrict__ pos,     // (B,N,3)
    const int*   __restrict__ xatom,   // (B,N)
    const float* __restrict__ means,   // (K)
    const float* __restrict__ stds,    // (K)
    const float* __restrict__ mul_w,   // (1536)
    const float* __restrict__ bias_w,  // (1536)
    _Float16* __restrict__ sumef)      // (B*N, K) fp16
{
    const int bi = blockIdx.x;
    const int b  = bi >> 8;
    const int t  = threadIdx.x;
    const int base = b << 8;

    __shared__ __align__(16) float y_sh[NN];
    __shared__ float part[256];

    const int   ai  = xatom[bi];
    const float pix = pos[bi*3+0], piy = pos[bi*3+1], piz = pos[bi*3+2];

    {
        const int j  = t;
        const int aj = xatom[base + j];
        const float dx = pix - pos[(base+j)*3+0];
        const float dy = piy - pos[(base+j)*3+1];
        const float dz = piz - pos[(base+j)*3+2];
        const float dist = sqrtf(dx*dx + dy*dy + dz*dz);
        const int idx = ai*128 + aj;
        float y = mul_w[idx]*dist + bias_w[idx];
        if (aj == 0) y = 1e20f;   // padded j -> exp underflows to 0
        y_sh[j] = y;
    }
    __syncthreads();

    const int k    = t & 127;
    const int half = t >> 7;
    const float m   = means[k];
    const float s   = fabsf(stds[k]) + 0.8f;
    const float inv = 1.0f / s;
    const float w   = inv * 0.84932160f;     // sqrt(0.5*log2e)
    const float nm  = -m * w;
    const float c   = inv * 0.39894253f;     // 1/sqrt(2*3.14159)

    float a0=0.f, a1=0.f, a2=0.f, a3=0.f;
    const float4* yv = (const float4*)(y_sh + (half << 7));
    #pragma unroll
    for (int j4 = 0; j4 < 32; ++j4) {
        float4 y4 = yv[j4];
        float d0 = fmaf(y4.x, w, nm); a0 += __builtin_amdgcn_exp2f(-(d0*d0));
        float d1 = fmaf(y4.y, w, nm); a1 += __builtin_amdgcn_exp2f(-(d1*d1));
        float d2 = fmaf(y4.z, w, nm); a2 += __builtin_amdgcn_exp2f(-(d2*d2));
        float d3 = fmaf(y4.w, w, nm); a3 += __builtin_amdgcn_exp2f(-(d3*d3));
    }
    part[t] = ((a0+a1)+(a2+a3)) * c;
    __syncthreads();

    if (t < 128)
        sumef[bi*KK + t] = (_Float16)(part[t] + part[t + 128]);
}

// ---------------- Kernel 2: MFMA projection GEMM -----------------
// C(2048x768) = S(2048x128,fp16) * W^T(128x768,fp16) + bias, row-masked.
// 768 blocks (64 row-blocks x 12 d-tiles) x 128 threads (2 waves).
// Wave computes a 16-row x 64-col strip: 4 col-frags x 4 k-steps of
// mfma_f32_16x16x32_f16, fragments loaded DIRECTLY from global (L1/L2).
__global__ __launch_bounds__(128) void k_proj(
    const _Float16* __restrict__ Sh,   // (2048,128)
    const _Float16* __restrict__ Wh,   // (768,128)
    const float* __restrict__ proj_b,  // (768)
    const int*   __restrict__ xatom,   // (2048)
    float* __restrict__ out)           // (2048,768)
{
    const int t    = threadIdx.x;
    const int lane = t & 63;
    const int wid  = t >> 6;                 // 0..1
    const int bid  = blockIdx.x;
    const int r0   = ((bid & 63) << 5) + (wid << 4);  // 64 row-blocks of 32
    const int d0   = (bid >> 6) << 6;                 // 12 d-tiles of 64

    const int lr = lane & 15;                // row (A) / col (B) within 16
    const int hi = lane >> 4;                // k-chunk 0..3 (8 halves each)

    const _Float16* arow = Sh + (r0 + lr)*KK + hi*8;
    const _Float16* bcol = Wh + (d0 + lr)*KK + hi*8;

    f32x4 acc[4] = {};
    #pragma unroll
    for (int ks = 0; ks < 4; ++ks) {
        half8 a = *(const half8*)(arow + ks*32);
        #pragma unroll
        for (int c = 0; c < 4; ++c) {
            half8 b = *(const half8*)(bcol + c*16*KK + ks*32);
            acc[c] = __builtin_amdgcn_mfma_f32_16x16x32_f16(a, b, acc[c], 0, 0, 0);
        }
    }

    // C/D layout (m89, verified): col = lane&15, row = (lane>>4)*4 + reg
    #pragma unroll
    for (int reg = 0; reg < 4; ++reg) {
        const int row   = r0 + hi*4 + reg;
        const bool valid = (xatom[row] != 0);
        #pragma unroll
        for (int c = 0; c < 4; ++c) {
            const int col = d0 + c*16 + lr;
            const float v = acc[c][reg] + proj_b[col];
            out[row*DD + col] = valid ? v : 0.0f;
        }
    }
}

extern "C" void kernel_launch(void* const* d_in, const int* in_sizes, int n_in,
                              void* d_out, int out_size, void* d_ws, size_t ws_size,
                              hipStream_t stream) {
    const float* pos    = (const float*)d_in[0];
    const int*   xatom  = (const int*)  d_in[1];
    const float* means  = (const float*)d_in[2];
    const float* stds   = (const float*)d_in[3];
    const float* mul_w  = (const float*)d_in[4];
    const float* bias_w = (const float*)d_in[5];
    const float* proj_w = (const float*)d_in[6];
    const float* proj_b = (const float*)d_in[7];
    float* out = (float*)d_out;

    _Float16* Sh = (_Float16*)d_ws;                           // 512 KB
    _Float16* Wh = (_Float16*)((char*)d_ws + 512*1024);       // 192 KB

    const int BN = in_sizes[1];   // B*N = 2048

    k_cvtw <<<(DD*KK)/(256*4), 256, 0, stream>>>(proj_w, Wh);
    k_edges<<<BN, 256, 0, stream>>>(pos, xatom, means, stds, mul_w, bias_w, Sh);
    k_proj <<<(BN/32)*(DD/64), 128, 0, stream>>>(Sh, Wh, proj_b, xatom, out);
}